// Round 13
// baseline (281.215 us; speedup 1.0000x reference)
//
#include <hip/hip_runtime.h>
#include <stdint.h>

#define NTOK   131072
#define DM     1024
#define NE     64
#define NBLK   1024       // gate blocks (256 thr = 4 indep waves x 32 tokens)
#define BK     32         // K chunk (floats)
#define NCHUNK 32         // DM / BK
#define CAP    2458       // ceil(1.2 * 131072 / 64)
#define TAU    0.002f     // rescue threshold: >> ~4e-5 2-plane split error bound

typedef __attribute__((ext_vector_type(8))) short bf16x8;
typedef __attribute__((ext_vector_type(4))) float f32x4;

union Frag { bf16x8 v; uint32_t w[4]; uint4 q; unsigned short u[8]; };

// RNE fp32 -> bf16 bits (wprep only)
__device__ __forceinline__ unsigned short f2bf_rne(float x) {
    uint32_t u = __float_as_uint(x);
    u += 0x7FFFu + ((u >> 16) & 1u);
    return (unsigned short)(u >> 16);
}
__device__ __forceinline__ float bf2f(unsigned short h) {
    return __uint_as_float(((uint32_t)h) << 16);
}

// ---------------------------------------------------------------------------
// wprep: split W (1024x64 fp32) into 2 bf16 planes in MFMA B-frag order.
// Wp[(c*8 + t*2 + p)*64 + l]: col = t*16+(l&15), k = c*32+(l>>4)*8+j.
// Also zeroes the rescue counter.
// ---------------------------------------------------------------------------
__global__ __launch_bounds__(256)
void wprep_kernel(const float* __restrict__ W, uint4* __restrict__ Wp, int* __restrict__ cnt)
{
    if (blockIdx.x == 0 && threadIdx.x == 0) *cnt = 0;
    const int c = blockIdx.x;          // k-chunk 0..31
    const int t = threadIdx.x >> 6;    // n-tile 0..3
    const int l = threadIdx.x & 63;
    Frag p1, p2;
#pragma unroll
    for (int j = 0; j < 8; ++j) {
        const float wv = W[(size_t)(c * 32 + (l >> 4) * 8 + j) * NE + t * 16 + (l & 15)];
        const unsigned short h1 = f2bf_rne(wv);
        const unsigned short h2 = f2bf_rne(wv - bf2f(h1));
        p1.u[j] = h1; p2.u[j] = h2;
    }
    uint4* base = Wp + (size_t)(c * 8 + t * 2) * 64;
    base[0 * 64 + l] = p1.q;
    base[1 * 64 + l] = p2.q;
}

// 2-plane split of 8 fp32 via packed HW convert (rounding-mode agnostic:
// the residual subtraction is exact for any rounding of the first plane).
struct ASet { float4 p00, p01, p10, p11; };

__device__ __forceinline__ void splitA(const float4& P0, const float4& P1,
                                       Frag& A1, Frag& A2)
{
    const float xs[8] = {P0.x, P0.y, P0.z, P0.w, P1.x, P1.y, P1.z, P1.w};
#pragma unroll
    for (int j = 0; j < 4; ++j) {
        uint32_t p1, p2;
        asm("v_cvt_pk_bf16_f32 %0, %1, %2" : "=v"(p1) : "v"(xs[2*j]), "v"(xs[2*j+1]));
        const float f0 = __uint_as_float(p1 << 16);
        const float f1 = __uint_as_float(p1 & 0xffff0000u);
        const float r0 = xs[2*j] - f0;
        const float r1 = xs[2*j+1] - f1;
        asm("v_cvt_pk_bf16_f32 %0, %1, %2" : "=v"(p2) : "v"(r0), "v"(r1));
        A1.w[j] = p1; A2.w[j] = p2;
    }
}

// ---------------------------------------------------------------------------
// gate_kernel (R13): ZERO LDS, ZERO barriers. 256 threads = 4 fully
// independent waves, each owning 32 tokens x 64 experts.
// R12 post-mortem: the A gload_lds->vmcnt->ds_read hop sat on the per-chunk
// critical path in every LDS variant (R10-R12 all ~270-320); R9 proved the
// direct per-lane A loads are fully coalesced (lane(g,e16) reads 32B of row
// e16/e16+16; a load-pair covers 16 rows x 128B) but died on occupancy
// (220 VGPR). R13 = direct loads AT 4 waves/SIMD: depth-1 A double-buffer
// (2x16 VGPR), just-in-time B from L2-resident Wp (no prefetch buffer),
// acc 32 -> ~120 VGPR under the (256,4) cap. Compiler-managed per-register
// vmcnt waits (precise for plain loads) replace all manual sync.
// 3-term split MFMA: a.w ~= a1w1 + a1w2 + a2w1 (err ~2e-5 << TAU).
// ---------------------------------------------------------------------------
__global__ __launch_bounds__(256, 4)
void gate_kernel(const float* __restrict__ A, const uint4* __restrict__ Wp,
                 const float* __restrict__ bias, const float* __restrict__ noise,
                 float* __restrict__ out, int* __restrict__ bi_arr,
                 int* __restrict__ list, int* __restrict__ cnt,
                 float* __restrict__ colpart)
{
    const int tid  = threadIdx.x;
    const int lane = tid & 63;
    const int w    = __builtin_amdgcn_readfirstlane(tid >> 6);
    const int wvid = blockIdx.x * 4 + w;     // global wave 0..4095
    const int tokBase = wvid * 32;
    const int g    = lane >> 4;
    const int e16  = lane & 15;

    f32x4 acc[2][4];
#pragma unroll
    for (int mt = 0; mt < 2; ++mt)
#pragma unroll
        for (int nt = 0; nt < 4; ++nt)
            acc[mt][nt] = (f32x4){0.f, 0.f, 0.f, 0.f};

    // A rows owned by this lane: mt=0 -> row e16, mt=1 -> row e16+16;
    // this lane's k-slice = floats [g*8, g*8+8) of each 32-float chunk.
    const float* aRow0 = A + (size_t)(tokBase + e16) * DM + g * 8;
    const float* aRow1 = aRow0 + (size_t)16 * DM;

#define LOADA(c, S)  { S.p00 = *(const float4*)(aRow0 + (c) * BK);       \
                       S.p01 = *(const float4*)(aRow0 + (c) * BK + 4);   \
                       S.p10 = *(const float4*)(aRow1 + (c) * BK);       \
                       S.p11 = *(const float4*)(aRow1 + (c) * BK + 4); }
#define COMPUTE(c, AS) {                                                 \
        uint4 B_[8];                                                     \
        _Pragma("unroll")                                                \
        for (int u_ = 0; u_ < 8; ++u_)                                   \
            B_[u_] = Wp[((size_t)(c) * 8 + u_) * 64 + lane];             \
        Frag a1_[2], a2_[2];                                             \
        splitA(AS.p00, AS.p01, a1_[0], a2_[0]);                          \
        splitA(AS.p10, AS.p11, a1_[1], a2_[1]);                          \
        _Pragma("unroll")                                                \
        for (int nt_ = 0; nt_ < 4; ++nt_) {                              \
            Frag b1_, b2_;                                               \
            b1_.q = B_[nt_ * 2];                                         \
            b2_.q = B_[nt_ * 2 + 1];                                     \
            _Pragma("unroll")                                            \
            for (int mt_ = 0; mt_ < 2; ++mt_) {                          \
                f32x4 d_ = acc[mt_][nt_];                                \
                d_ = __builtin_amdgcn_mfma_f32_16x16x32_bf16(a1_[mt_].v, b1_.v, d_, 0, 0, 0); \
                d_ = __builtin_amdgcn_mfma_f32_16x16x32_bf16(a1_[mt_].v, b2_.v, d_, 0, 0, 0); \
                d_ = __builtin_amdgcn_mfma_f32_16x16x32_bf16(a2_[mt_].v, b1_.v, d_, 0, 0, 0); \
                acc[mt_][nt_] = d_;                                      \
            }                                                            \
        }                                                                \
    }

    ASet As0, As1;
    LOADA(0, As0)
#pragma unroll 1
    for (int cc = 0; cc < NCHUNK; cc += 2) {
        LOADA(cc + 1, As1)                   // cc+1 <= 31 always
        COMPUTE(cc, As0)
        if (cc + 2 < NCHUNK) LOADA(cc + 2, As0)
        COMPUTE(cc + 1, As1)
    }
#undef COMPUTE
#undef LOADA

    // ---- epilogue: bias+noise, per-token argmax/softmax, rescue-list ----
    // C/D: token = mt*16 + g*4 + r (row), expert = nt*16 + e16 (col) [m89]
#pragma unroll
    for (int mt = 0; mt < 2; ++mt)
#pragma unroll
        for (int r = 0; r < 4; ++r) {
            const int T = tokBase + mt * 16 + g * 4 + r;
#pragma unroll
            for (int nt = 0; nt < 4; ++nt) {
                const float nz = noise[(size_t)T * NE + nt * 16 + e16];
                acc[mt][nt][r] += bias[nt * 16 + e16] + nz * 0.2f + 0.9f;
            }
        }

    float cw[4] = {0.f, 0.f, 0.f, 0.f};
#pragma unroll
    for (int mt = 0; mt < 2; ++mt)
#pragma unroll
        for (int r = 0; r < 4; ++r) {
            const int T = tokBase + mt * 16 + g * 4 + r;
            float raw[4];
#pragma unroll
            for (int nt = 0; nt < 4; ++nt) raw[nt] = acc[mt][nt][r];

            float v = raw[0]; int be = e16;
#pragma unroll
            for (int nt = 1; nt < 4; ++nt)
                if (raw[nt] > v) { v = raw[nt]; be = nt * 16 + e16; }
#pragma unroll
            for (int m = 1; m <= 8; m <<= 1) {
                const float vo = __shfl_xor(v, m, 64);
                const int   eo = __shfl_xor(be, m, 64);
                if (vo > v || (vo == v && eo < be)) { v = vo; be = eo; }
            }
            float m2 = -1e30f;                          // runner-up
#pragma unroll
            for (int nt = 0; nt < 4; ++nt)
                if (nt * 16 + e16 != be && raw[nt] > m2) m2 = raw[nt];
#pragma unroll
            for (int m = 1; m <= 8; m <<= 1)
                m2 = fmaxf(m2, __shfl_xor(m2, m, 64));

            float d = 0.f, pr[4];
#pragma unroll
            for (int nt = 0; nt < 4; ++nt) { pr[nt] = __expf(raw[nt] - v); d += pr[nt]; }
#pragma unroll
            for (int m = 1; m <= 8; m <<= 1) d += __shfl_xor(d, m, 64);
            const float inv = 1.0f / d;
#pragma unroll
            for (int nt = 0; nt < 4; ++nt) cw[nt] += pr[nt] * inv;

            if (e16 == mt * 4 + r) {                    // one writer per (g,mt,r)
                out[NTOK + T] = inv;
                bi_arr[T]     = be;
                if (v - m2 < TAU) {                     // borderline -> rescue
                    const int s = atomicAdd(cnt, 1);
                    list[s] = T;
                }
            }
        }

    // per-expert column sums over this wave's 32 tokens
#pragma unroll
    for (int nt = 0; nt < 4; ++nt) {
        cw[nt] += __shfl_xor(cw[nt], 16, 64);
        cw[nt] += __shfl_xor(cw[nt], 32, 64);
    }
    if (lane < 16) {
#pragma unroll
        for (int nt = 0; nt < 4; ++nt)
            colpart[wvid * NE + nt * 16 + lane] = cw[nt];
    }
}

// ---------------------------------------------------------------------------
// rescue: recompute listed tokens with the bit-identical R5 sequential-fmaf
// chain (k ascending) so borderline argmax decisions match the fp32 path.
// ---------------------------------------------------------------------------
__device__ __forceinline__ void rescue_finish(int t, float sc, int lane,
                                              int* bi_arr, float* out)
{
    float v = sc; int be = lane;
#pragma unroll
    for (int m = 1; m <= 32; m <<= 1) {
        const float vo = __shfl_xor(v, m, 64);
        const int   eo = __shfl_xor(be, m, 64);
        if (vo > v || (vo == v && eo < be)) { v = vo; be = eo; }
    }
    float d = __expf(sc - v);
#pragma unroll
    for (int m = 1; m <= 32; m <<= 1) d += __shfl_xor(d, m, 64);
    if (lane == 0) { bi_arr[t] = be; out[NTOK + t] = 1.0f / d; }
}

__global__ __launch_bounds__(64)
void rescue_kernel(const float* __restrict__ A, const float* __restrict__ W,
                   const float* __restrict__ bias, const float* __restrict__ noise,
                   const int* __restrict__ list, const int* __restrict__ cnt,
                   int* __restrict__ bi_arr, float* __restrict__ out)
{
    const int lane = threadIdx.x;
    const int n = *cnt;
#pragma unroll 1
    for (int i0 = blockIdx.x * 4; i0 < n; i0 += 256 * 4) {
        const int t0 = list[i0];
        const int t1 = (i0 + 1 < n) ? list[i0 + 1] : t0;
        const int t2 = (i0 + 2 < n) ? list[i0 + 2] : t0;
        const int t3 = (i0 + 3 < n) ? list[i0 + 3] : t0;
        const float* r0 = A + (size_t)t0 * DM;
        const float* r1 = A + (size_t)t1 * DM;
        const float* r2 = A + (size_t)t2 * DM;
        const float* r3 = A + (size_t)t3 * DM;
        float a0 = 0.f, a1 = 0.f, a2 = 0.f, a3 = 0.f;
#pragma unroll 4
        for (int k = 0; k < DM; ++k) {
            const float wk = W[(size_t)k * NE + lane];
            a0 = fmaf(r0[k], wk, a0);
            a1 = fmaf(r1[k], wk, a1);
            a2 = fmaf(r2[k], wk, a2);
            a3 = fmaf(r3[k], wk, a3);
        }
        const float bl = bias[lane];
        rescue_finish(t0, a0 + bl + noise[(size_t)t0 * NE + lane] * 0.2f + 0.9f, lane, bi_arr, out);
        rescue_finish(t1, a1 + bl + noise[(size_t)t1 * NE + lane] * 0.2f + 0.9f, lane, bi_arr, out);
        rescue_finish(t2, a2 + bl + noise[(size_t)t2 * NE + lane] * 0.2f + 0.9f, lane, bi_arr, out);
        rescue_finish(t3, a3 + bl + noise[(size_t)t3 * NE + lane] * 0.2f + 0.9f, lane, bi_arr, out);
    }
}

// ---------------------------------------------------------------------------
// rank: stable within-128-token-block rank + histogram via ballots.
// ---------------------------------------------------------------------------
__global__ __launch_bounds__(64)
void rank_kernel(const int* __restrict__ bi_arr, int* __restrict__ pk,
                 int* __restrict__ histg)
{
    const int b    = blockIdx.x;
    const int lane = threadIdx.x;
    const uint64_t below = (1ull << lane) - 1ull;
    const int t0 = b * 128;
    const int b0 = bi_arr[t0 + lane];
    const int b1 = bi_arr[t0 + 64 + lane];
    int lr0 = 0, lr1 = 0, h0 = 0, h1 = 0, h0my = 0;
#pragma unroll 1
    for (int e = 0; e < NE; ++e) {
        const uint64_t m0 = __ballot(b0 == e);
        const uint64_t m1 = __ballot(b1 == e);
        if (b0 == e)   lr0 = (int)__popcll(m0 & below);
        if (b1 == e) { lr1 = (int)__popcll(m1 & below); h0my = (int)__popcll(m0); }
        if (lane == e) { h0 = (int)__popcll(m0); h1 = (int)__popcll(m1); }
    }
    pk[t0 + lane]      = b0 | (lr0 << 6);
    pk[t0 + 64 + lane] = b1 | ((lr1 + h0my) << 6);
    histg[b * NE + lane] = h0 + h1;
}

// ---------------------------------------------------------------------------
// scan: per-expert exclusive scan over 1024 rank-block histograms (in-place)
// + per-expert totals and softmax column sums (colpart: 4096 waves x 64).
// ---------------------------------------------------------------------------
__global__ __launch_bounds__(256)
void scan_kernel(int* __restrict__ hist, const float* __restrict__ colpart,
                 int* __restrict__ totals, float* __restrict__ colsums)
{
    __shared__ int   wtot[4];
    __shared__ float wcs[4];
    const int e = blockIdx.x, t = threadIdx.x, lane = t & 63, w = t >> 6;

    int h[4]; int s = 0; float csl = 0.f;
#pragma unroll
    for (int i = 0; i < 4; ++i) {
        h[i] = hist[(t * 4 + i) * NE + e];
        s   += h[i];
    }
#pragma unroll
    for (int i = 0; i < 16; ++i)
        csl += colpart[(t * 16 + i) * NE + e];

    int inc = s;
#pragma unroll
    for (int d = 1; d < 64; d <<= 1) {
        const int v = __shfl_up(inc, d, 64);
        if (lane >= d) inc += v;
    }
    float wsum = csl;
#pragma unroll
    for (int m = 32; m; m >>= 1) wsum += __shfl_xor(wsum, m, 64);
    if (lane == 63) wtot[w] = inc;
    if (lane == 0)  wcs[w]  = wsum;
    __syncthreads();

    int base = 0;
#pragma unroll
    for (int ww = 0; ww < 4; ++ww) base += (ww < w) ? wtot[ww] : 0;
    int run = base + inc - s;
#pragma unroll
    for (int i = 0; i < 4; ++i) { hist[(t * 4 + i) * NE + e] = run; run += h[i]; }

    if (t == 0) {
        totals[e]  = wtot[0] + wtot[1] + wtot[2] + wtot[3];
        colsums[e] = wcs[0] + wcs[1] + wcs[2] + wcs[3];
    }
}

__global__ void loss_kernel(const int* __restrict__ totals,
                            const float* __restrict__ colsums,
                            float* __restrict__ out)
{
    const int e   = threadIdx.x;
    const int tot = totals[e];
    const float cnt = (float)((tot < CAP) ? tot : CAP);
    float nv = cnt, contrib = cnt * colsums[e];
#pragma unroll
    for (int m = 32; m; m >>= 1) {
        nv      += __shfl_xor(nv, m, 64);
        contrib += __shfl_xor(contrib, m, 64);
    }
    if (e == 0) out[2 * NTOK] = 64.0f * contrib / (nv * nv);
}

__global__ void finalize_kernel(const int* __restrict__ pk, const int* __restrict__ offs,
                                float* __restrict__ out)
{
    const int i = blockIdx.x * 256 + threadIdx.x;
    const int v = pk[i];
    const int e = v & 63;
    const int r = (v >> 6) + offs[(i >> 7) * NE + e];
    out[i] = (r < CAP) ? (float)e : -1.0f;
}

extern "C" void kernel_launch(void* const* d_in, const int* in_sizes, int n_in,
                              void* d_out, int out_size, void* d_ws, size_t ws_size,
                              hipStream_t stream)
{
    (void)in_sizes; (void)n_in; (void)out_size; (void)ws_size;
    const float* A     = (const float*)d_in[0];
    const float* W     = (const float*)d_in[1];
    const float* bias  = (const float*)d_in[2];
    const float* noise = (const float*)d_in[3];
    float* out = (float*)d_out;

    char* ws = (char*)d_ws;
    int*   bi_arr  = (int*)ws;                         // 512 KB
    int*   list    = (int*)(ws + 524288);              // 512 KB (gate->rescue)
    int*   pk      = (int*)(ws + 524288);              // aliased: rank(after rescue)->finalize
    int*   histg   = (int*)(ws + 1048576);             // 256 KB (offsets in-place)
    float* colpart = (float*)(ws + 1310720);           // 1 MB (4096 waves x 64)
    int*   totals  = (int*)(ws + 2359296);             // 256 B
    float* colsums = (float*)(ws + 2359552);           // 256 B
    int*   cnt     = (int*)(ws + 2359808);             // 4 B
    uint4* Wp      = (uint4*)(ws + 2363392);           // 256 KB (2 bf16 planes, frag order)

    wprep_kernel<<<NCHUNK, 256, 0, stream>>>(W, Wp, cnt);
    gate_kernel<<<NBLK, 256, 0, stream>>>(A, Wp, bias, noise, out, bi_arr, list, cnt, colpart);
    rescue_kernel<<<256, 64, 0, stream>>>(A, W, bias, noise, list, cnt, bi_arr, out);
    rank_kernel<<<NTOK / 128, 64, 0, stream>>>(bi_arr, pk, histg);
    scan_kernel<<<NE, 256, 0, stream>>>(histg, colpart, totals, colsums);
    loss_kernel<<<1, 64, 0, stream>>>(totals, colsums, out);
    finalize_kernel<<<NTOK / 256, 256, 0, stream>>>(pk, histg, out);
}